// Round 1
// baseline (111.148 us; speedup 1.0000x reference)
//
#include <hip/hip_runtime.h>

// Hankel anti-diagonal segmented mean.
// Input:  delay_embedding [B=64, T=1024, E=2048] fp32
// Output: [B, E-1=2047] fp32; out[b,k] = mean over i of A[b, i, 1024+k-i]
//         for i in [max(0, k-1023), 1023].

#define T_LEN 1024
#define E_LEN 2048
#define K_OUT (E_LEN - 1)      // 2047 output diagonals
#define B_SZ  64
#define NSPLIT 4               // split i-range for occupancy / load balance
#define CHUNK (T_LEN / NSPLIT) // 256

__global__ void __launch_bounds__(256)
diag_accum(const float* __restrict__ in, float* __restrict__ out) {
    const int k = blockIdx.x * blockDim.x + threadIdx.x;   // output diagonal
    if (k >= K_OUT) return;
    const int b = blockIdx.y;
    const int z = blockIdx.z;

    int i_lo = z * CHUNK;
    const int i_hi = i_lo + CHUNK;          // exclusive; <= T_LEN always
    const int k_lo = k - (T_LEN - 1);       // first valid row for this k
    if (k_lo > i_lo) i_lo = k_lo;
    if (i_lo >= i_hi) return;

    // A[b, i, 1024 + k - i] = in[b*T*E + i*(E-1) + (T + k)]
    const float* p = in + (size_t)b * T_LEN * E_LEN
                        + (size_t)i_lo * (E_LEN - 1)
                        + (size_t)(T_LEN + k);
    float s = 0.0f;
    #pragma unroll 8
    for (int i = i_lo; i < i_hi; ++i) {
        s += *p;                 // per-wave: 64 consecutive floats -> coalesced
        p += (E_LEN - 1);        // next row, same diagonal
    }
    atomicAdd(&out[(size_t)b * K_OUT + k], s);   // <= NSPLIT adds per slot
}

__global__ void __launch_bounds__(256)
diag_finalize(float* __restrict__ out) {
    const int idx = blockIdx.x * blockDim.x + threadIdx.x;
    if (idx >= B_SZ * K_OUT) return;
    const int k = idx % K_OUT;
    const int over = k - (T_LEN - 1);
    const int cnt = T_LEN - (over > 0 ? over : 0);  // 1024 or 3071-s
    out[idx] *= (1.0f / (float)cnt);
}

extern "C" void kernel_launch(void* const* d_in, const int* in_sizes, int n_in,
                              void* d_out, int out_size, void* d_ws, size_t ws_size,
                              hipStream_t stream) {
    const float* in = (const float*)d_in[0];
    float* out = (float*)d_out;

    // Zero the accumulator (d_out is poisoned once and never re-poisoned).
    hipMemsetAsync(out, 0, sizeof(float) * B_SZ * K_OUT, stream);

    dim3 grid((K_OUT + 255) / 256, B_SZ, NSPLIT);
    diag_accum<<<grid, 256, 0, stream>>>(in, out);

    const int tot = B_SZ * K_OUT;
    diag_finalize<<<(tot + 255) / 256, 256, 0, stream>>>(out);
}

// Round 2
// 102.450 us; speedup vs baseline: 1.0849x; 1.0849x over previous
//
#include <hip/hip_runtime.h>

// Hankel anti-diagonal segmented mean.
// Input:  delay_embedding [B=64, T=1024, E=2048] fp32
// Output: [B, E-1=2047] fp32; out[b,k] = mean over i of A[b, i, 1024+k-i]
//         for i in [max(0, k-1023), 1023].
//
// Strategy: for fixed row i, the diagonal elements for consecutive k are
// CONTIGUOUS in memory (A[b, i, 1024+k-i]), so lanes mapped to k give fully
// coalesced 256 B wave segments; every needed input element is read exactly
// once (402 MB total -> HBM-bound, ~64 us floor).
// Each thread pre-scales its partial sum by 1/cnt(k) so the atomicAdd's
// accumulate directly into the final mean -> no finalize kernel.

#define T_LEN 1024
#define E_LEN 2048
#define K_OUT (E_LEN - 1)      // 2047 output diagonals
#define B_SZ  64
#define NSPLIT 4               // split i-range: 2048 blocks -> good balance/occupancy
#define CHUNK (T_LEN / NSPLIT) // 256

__global__ void __launch_bounds__(256)
diag_accum(const float* __restrict__ in, float* __restrict__ out) {
    const int k = blockIdx.x * blockDim.x + threadIdx.x;   // output diagonal
    if (k >= K_OUT) return;
    const int b = blockIdx.y;
    const int z = blockIdx.z;

    int i_lo = z * CHUNK;
    const int i_hi = i_lo + CHUNK;          // exclusive; <= T_LEN always
    const int k_lo = k - (T_LEN - 1);       // first valid row for this k
    if (k_lo > i_lo) i_lo = k_lo;
    if (i_lo >= i_hi) return;

    // diagonal length: 1024 for k < 1024, tapering 1023..1 above
    const int over = k - (T_LEN - 1);
    const int cnt = T_LEN - (over > 0 ? over : 0);
    const float scale = 1.0f / (float)cnt;  // once per thread; exactness not needed (thr 4.9e-2)

    // A[b, i, 1024 + k - i] = in[b*T*E + i*(E-1) + (T + k)]
    const float* p = in + (size_t)b * T_LEN * E_LEN
                        + (size_t)i_lo * (E_LEN - 1)
                        + (size_t)(T_LEN + k);
    float s = 0.0f;
    #pragma unroll 16
    for (int i = i_lo; i < i_hi; ++i) {
        s += *p;                 // per-wave: 64 consecutive floats -> coalesced
        p += (E_LEN - 1);        // next row, same diagonal
    }
    atomicAdd(&out[(size_t)b * K_OUT + k], s * scale);   // <= NSPLIT adds per slot
}

extern "C" void kernel_launch(void* const* d_in, const int* in_sizes, int n_in,
                              void* d_out, int out_size, void* d_ws, size_t ws_size,
                              hipStream_t stream) {
    const float* in = (const float*)d_in[0];
    float* out = (float*)d_out;

    // Zero the accumulator (d_out is poisoned once and never re-poisoned).
    hipMemsetAsync(out, 0, sizeof(float) * B_SZ * K_OUT, stream);

    dim3 grid((K_OUT + 255) / 256, B_SZ, NSPLIT);
    diag_accum<<<grid, 256, 0, stream>>>(in, out);
}

// Round 3
// 94.647 us; speedup vs baseline: 1.1743x; 1.0824x over previous
//
#include <hip/hip_runtime.h>

// Hankel anti-diagonal segmented mean.
// Input:  delay_embedding [B=64, T=1024, E=2048] fp32
// Output: [B, E-1=2047] fp32; out[b,k] = mean over i of A[b, i, 1024+k-i],
//         i in [max(0, k-1023), 1023].
//
// For fixed row i, diagonal elements for consecutive k are contiguous:
// A[b,i,1024+k-i] = in[b*T*E + i*(E-1) + (T+k)].  Lanes map to k -> fully
// coalesced; each input element read exactly once (402 MB, HBM-bound).
// Threads own 4 consecutive k (float4 loads, 16B/lane), pre-scale partial
// sums by 1/cnt(k), atomicAdd into d_out (<=4 adds/slot, zeroed by memset).
//
// Grid is 1-D with the k-block index x in the HIGH bits: a CU's stride-256
// round-robin share spans x=0..3 (two full blocks + two tapered), and x=3
// uses a z-permutation so every CU gets ~equal total work.

#define T_LEN 1024
#define E_LEN 2048
#define K_OUT (E_LEN - 1)   // 2047
#define B_SZ  64
#define NZ    4
#define ROWS  (T_LEN / NZ)  // 256
#define TPB   128
#define NBLK  (NZ * B_SZ * 4)  // 1024 blocks

__global__ void __launch_bounds__(TPB)
diag_accum(const float* __restrict__ in, float* __restrict__ out) {
    const int bid  = blockIdx.x;
    const int zraw = bid & (NZ - 1);
    const int b    = (bid >> 2) & (B_SZ - 1);
    const int x    = bid >> 8;                 // k-block 0..3 (high bits!)

    // z-perm {3,2,0,1} for x==3 pairs taper profiles so per-CU work is flat
    int z = zraw;
    if (x == 3) z = (zraw < 2) ? (3 - zraw) : (zraw - 2);

    const int g  = x * TPB + threadIdx.x;      // k-group 0..511
    const int k0 = g << 2;                     // k = k0..k0+3 (k0 <= 2044)
    const int r0 = z * ROWS;
    const int r1 = r0 + ROWS;

    const int il0 = max(r0, k0     - (T_LEN - 1));
    const int il3 = max(r0, k0 + 3 - (T_LEN - 1));
    if (il0 >= r1) return;

    const float* p = in + (size_t)b * T_LEN * E_LEN
                        + (size_t)il0 * (E_LEN - 1)
                        + (size_t)(T_LEN + k0);
    float sx = 0.f, sy = 0.f, sz = 0.f, sw = 0.f;
    int i = il0;

    // Ragged taper head (<=3 iters): scalar loads, comp 3 never active here.
    // (Scalar also avoids reading past the buffer at the b=63, k0=2044 corner.)
    const int head_end = min(il3, r1);
    for (; i < head_end; ++i) {
        sx += p[0];
        if (i >= k0 + 1 - (T_LEN - 1)) sy += p[1];
        if (i >= k0 + 2 - (T_LEN - 1)) sz += p[2];
        p += (E_LEN - 1);
    }

    // Main loop: all 4 components valid and in-bounds (no row wrap).
    #pragma unroll 8
    for (; i < r1; ++i) {
        float v[4];
        __builtin_memcpy(v, p, 16);   // unaligned-safe 16B load -> dwordx4
        sx += v[0]; sy += v[1]; sz += v[2]; sw += v[3];
        p += (E_LEN - 1);
    }

    // Pre-scale by 1/cnt(k) so atomics accumulate the final mean directly.
    const int ov = k0 - (T_LEN - 1);
    const float n0 = (float)(T_LEN - max(0, ov));
    const float n1 = (float)(T_LEN - max(0, ov + 1));
    const float n2 = (float)(T_LEN - max(0, ov + 2));
    float* o = out + (size_t)b * K_OUT + k0;
    atomicAdd(o + 0, sx * (1.0f / n0));
    atomicAdd(o + 1, sy * (1.0f / n1));
    atomicAdd(o + 2, sz * (1.0f / n2));
    if (k0 + 3 < K_OUT) {
        const float n3 = (float)(T_LEN - max(0, ov + 3));
        atomicAdd(o + 3, sw * (1.0f / n3));
    }
}

extern "C" void kernel_launch(void* const* d_in, const int* in_sizes, int n_in,
                              void* d_out, int out_size, void* d_ws, size_t ws_size,
                              hipStream_t stream) {
    const float* in = (const float*)d_in[0];
    float* out = (float*)d_out;

    // Zero the accumulator (d_out is poisoned once, never re-poisoned).
    hipMemsetAsync(out, 0, sizeof(float) * B_SZ * K_OUT, stream);

    diag_accum<<<NBLK, TPB, 0, stream>>>(in, out);
}